// Round 4
// baseline (237.784 us; speedup 1.0000x reference)
//
#include <hip/hip_runtime.h>
#include <hip/hip_bf16.h>

#define H  32
#define W  32
#define CI 32
#define CO 64
#define NB 8
#define NOUT 32

// d_out float offsets: [w_u | b_u | w_l | b_l]
#define WU_OFF 0
#define BU_OFF (NB * H * W * CI * NOUT)          // 8388608
#define WL_OFF (BU_OFF + NB * NOUT)              // 8388864
#define BL_OFF (WL_OFF + NB * H * W * CI * NOUT) // 16777472

// d_ws layout:
//   [0, 36864)       bf16 A-fragments (2304 uint4)
//   [36864, 38912)   fp32 bias partials bp[16][32]
#define KF_UINT4 2304
#define BP_OFF_BYTES 36864

typedef __bf16 bf16x8 __attribute__((ext_vector_type(8)));
typedef float  f32x4  __attribute__((ext_vector_type(4)));

__device__ __forceinline__ unsigned int pack_bf16(float lo, float hi) {
    unsigned int ulo = __float_as_uint(lo) + 0x8000u;
    unsigned int uhi = __float_as_uint(hi) + 0x8000u;
    return (uhi & 0xffff0000u) | (ulo >> 16);
}

// Swizzle conv kernel K[3][3][32][64] fp32 -> bf16 A-fragments (HW-verified R1-R4).
// Blocks 9,10 zero the fp32 bias-partial buffer.
__global__ void prep_kernel(const float* __restrict__ K,
                            unsigned int* __restrict__ kws,
                            float* __restrict__ bp) {
    int bx = blockIdx.x, t = threadIdx.x;
    if (bx < 9) {
        int g    = bx * 256 + t;
        int tap  = g >> 8;
        int r    = g & 255;
        int i    = r >> 3;
        int og   = r & 7;
        int c    = og >> 2;
        int quad = og & 3;
        int ih   = i >> 4;
        int lane = quad * 16 + (i & 15);
        int dst  = ((tap * 4 + c * 2 + ih) * 64 + lane) * 4;
        const float4* src = (const float4*)(K + (size_t)g * 8);
        float4 f0 = src[0];
        float4 f1 = src[1];
        kws[dst + 0] = pack_bf16(f0.x, f0.y);
        kws[dst + 1] = pack_bf16(f0.z, f0.w);
        kws[dst + 2] = pack_bf16(f1.x, f1.y);
        kws[dst + 3] = pack_bf16(f1.z, f1.w);
    } else {
        bp[(bx - 9) * 256 + t] = 0.f;
    }
}

// Fused transpose+conv v3: 512-thread blocks (8 waves), wave = one w-position.
// stg 60 KB -> 2 blocks/CU = 16 waves/CU (50% occ; R3 had 8 waves = the
// latency-bound culprit). VGPR held <=128 via __launch_bounds__(512,4).
// kf in regs (18 bf16x8 from global, L1/L2-resident). Swizzle slot
// og'*32 + ((n^(n>>2))^og'): conflict-free writes AND reads (R3-verified, 0 conflicts).
__global__ __launch_bounds__(512, 4)
void fused_conv_kernel(const float* __restrict__ in0,
                       const float* __restrict__ in1,
                       const uint4* __restrict__ kws,
                       const float* __restrict__ bias,
                       float* __restrict__ bp,       // bp[16][32], pre-zeroed
                       float* __restrict__ out0,
                       float* __restrict__ out1) {
    __shared__ uint4 stg[30 * 128];    // 61440 B: [row*10+col][128 swizzled]
    __shared__ float bias_s[CO];
    __shared__ float bsum[8][32];      // per-wave bias partials

    int t = threadIdx.x;
    if (t < CO) bias_s[t] = bias[t];

    // XCD-aware swizzle: 2048 blocks, XCD = bx&7 gets 2 contiguous (side,b)
    // slabs, h-major walk inside -> 3-row fp32 window stays L2-resident.
    int bx    = blockIdx.x;
    int x     = bx & 7;
    int q     = bx >> 3;              // 0..255
    int combo = x * 2 + (q >> 7);     // (side,b) 0..15
    int idx   = q & 127;
    int side  = combo >> 3;
    int b     = combo & 7;
    int h     = idx >> 2;
    int wq    = idx & 3;              // w-octet 0..3

    const float* inp = (side ? in1 : in0) + (size_t)b * 1024 * 2048;
    const bf16x8* kfp = (const bf16x8*)kws;

    // staging coords: unit (32 lanes) stages one tile; 16 units cover 30 tiles in 2 steps
    int unit = t >> 5;        // 0..15
    int ogp  = (t >> 3) & 3;  // og' within co-half
    int n4   = t & 7;
    // mfma coords: wave owns position w = wq*8 + wave
    int wave = t >> 6;        // 0..7
    int lane = t & 63;
    int n16  = lane & 15;
    int quad = lane >> 4;
    int w    = wq * 8 + wave;

    f32x4 acc[2][2] = {};     // [ih][nh]
    float sb[4] = {0.f, 0.f, 0.f, 0.f};
    int rbase = quad * 32 + ((n16 ^ (n16 >> 2)) ^ quad);   // b1 slot = rbase^20

    __syncthreads();          // bias_s ready

    for (int c = 0; c < 2; c++) {
        // ---- A-fragment preload for this c-half (L1/L2-resident, issue early) ----
        bf16x8 a[9][2];
#pragma unroll
        for (int tap = 0; tap < 9; tap++) {
            a[tap][0] = kfp[(tap * 4 + c * 2 + 0) * 64 + lane];
            a[tap][1] = kfp[(tap * 4 + c * 2 + 1) * 64 + lane];
        }
        // ---- stage c-half of 30 halo tiles ----
#pragma unroll
        for (int s = 0; s < 2; s++) {
            int tile = s * 16 + unit;         // 0..31
            if (tile < 30) {
                int row = tile >= 20 ? 2 : (tile >= 10 ? 1 : 0);
                int col = tile - row * 10;    // 0..9
                int hi  = h - 1 + row;
                int wi  = wq * 8 - 1 + col;
                if (hi >= 0 && hi < H && wi >= 0 && wi < W) {
                    const float* p = inp + (size_t)(hi * W + wi) * 2048
                                   + c * 1024 + ogp * 256 + n4 * 4;
                    float v[8][4];
#pragma unroll
                    for (int j = 0; j < 8; j++) {
                        float4 f = *(const float4*)(p + j * 32);  // 16 B/lane
                        v[j][0] = f.x; v[j][1] = f.y; v[j][2] = f.z; v[j][3] = f.w;
                    }
                    // bias einsum on owned positions only (row==1, col 1..8)
                    if (row == 1 && col >= 1 && col <= 8) {
#pragma unroll
                        for (int j = 0; j < 8; j++) {
                            float bj = bias_s[c * 32 + ogp * 8 + j];
#pragma unroll
                            for (int k = 0; k < 4; k++)
                                sb[k] = fmaf(v[j][k], bj, sb[k]);
                        }
                    }
                    uint4* dst = &stg[tile * 128 + ogp * 32];
#pragma unroll
                    for (int k = 0; k < 4; k++) {
                        uint4 u;
                        u.x = pack_bf16(v[0][k], v[1][k]);
                        u.y = pack_bf16(v[2][k], v[3][k]);
                        u.z = pack_bf16(v[4][k], v[5][k]);
                        u.w = pack_bf16(v[6][k], v[7][k]);
                        int n = n4 * 4 + k;
                        dst[(n ^ (n >> 2)) ^ ogp] = u;
                    }
                }
            }
        }
        __syncthreads();
        // ---- MFMA phase (verified fragment maps; A from regs) ----
        __builtin_amdgcn_s_setprio(1);
#pragma unroll
        for (int kh = 0; kh < 3; kh++) {
            int hi = h + 1 - kh;
            if (hi < 0 || hi >= H) continue;
            int row = 2 - kh;
#pragma unroll
            for (int kw = 0; kw < 3; kw++) {
                int wi = w + 1 - kw;
                if (wi < 0 || wi >= W) continue;
                int col = wave + 2 - kw;      // 0..9
                int tap = kh * 3 + kw;
                const uint4* Tp = &stg[(row * 10 + col) * 128];
                union { uint4 u; bf16x8 v; } b0, b1;
                b0.u = Tp[rbase];
                b1.u = Tp[rbase ^ 20];
                acc[0][0] = __builtin_amdgcn_mfma_f32_16x16x32_bf16(a[tap][0], b0.v, acc[0][0], 0, 0, 0);
                acc[0][1] = __builtin_amdgcn_mfma_f32_16x16x32_bf16(a[tap][0], b1.v, acc[0][1], 0, 0, 0);
                acc[1][0] = __builtin_amdgcn_mfma_f32_16x16x32_bf16(a[tap][1], b0.v, acc[1][0], 0, 0, 0);
                acc[1][1] = __builtin_amdgcn_mfma_f32_16x16x32_bf16(a[tap][1], b1.v, acc[1][1], 0, 0, 0);
            }
        }
        __builtin_amdgcn_s_setprio(0);
        if (c == 0) __syncthreads();          // protect stg overwrite
    }

    // bias: butterfly over lane bits 3,4,5 (og' + unit parity), stage per-wave
    // partials in LDS, one 32-atomic set per block (8x fewer atomics than R3).
#pragma unroll
    for (int off = 8; off <= 32; off <<= 1)
#pragma unroll
        for (int k = 0; k < 4; k++)
            sb[k] += __shfl_xor(sb[k], off, 64);
    if (lane < 8) {
#pragma unroll
        for (int k = 0; k < 4; k++)
            bsum[wave][lane * 4 + k] = sb[k];
    }
    __syncthreads();
    if (t < 32) {
        float s = 0.f;
#pragma unroll
        for (int wv = 0; wv < 8; wv++) s += bsum[wv][t];
        atomicAdd(&bp[side * 256 + b * 32 + t], s);
    }

    // store (same per-lane map as verified R2/R3)
    float* outp = (side ? out1 : out0) + (size_t)b * (H * W * CI * NOUT);
    float* wout = outp + (size_t)((h * W + w) * CI) * NOUT;
#pragma unroll
    for (int ih = 0; ih < 2; ih++)
#pragma unroll
        for (int nh = 0; nh < 2; nh++)
#pragma unroll
            for (int r = 0; r < 4; r++) {
                int i = ih * 16 + quad * 4 + r;
                int n = nh * 16 + n16;
                wout[i * NOUT + n] = acc[ih][nh][r];
            }
}

// Bias finalize: b = b_in + bp
__global__ void bias_final32_kernel(const float* __restrict__ bp,
                                    const float* __restrict__ bu,
                                    const float* __restrict__ bl,
                                    float* __restrict__ out) {
    int sb = blockIdx.x;             // 0..15
    int t  = threadIdx.x;
    if (t >= NOUT) return;
    int side = sb >> 3, b = sb & 7;
    const float* bb = side ? bl : bu;
    out[(side ? BL_OFF : BU_OFF) + b * NOUT + t] =
        bb[b * NOUT + t] + bp[sb * 32 + t];
}

extern "C" void kernel_launch(void* const* d_in, const int* in_sizes, int n_in,
                              void* d_out, int out_size, void* d_ws, size_t ws_size,
                              hipStream_t stream) {
    const float* wu   = (const float*)d_in[0];
    const float* bu   = (const float*)d_in[1];
    const float* wl   = (const float*)d_in[2];
    const float* bl   = (const float*)d_in[3];
    const float* K    = (const float*)d_in[4];
    const float* bias = (const float*)d_in[5];
    float* out = (float*)d_out;
    unsigned int* kws = (unsigned int*)d_ws;
    float* bp = (float*)((char*)d_ws + BP_OFF_BYTES);

    prep_kernel<<<dim3(11), dim3(256), 0, stream>>>(K, kws, bp);
    fused_conv_kernel<<<dim3(2048), dim3(512), 0, stream>>>(
        wu, wl, (const uint4*)d_ws, bias, bp, out + WU_OFF, out + WL_OFF);
    bias_final32_kernel<<<dim3(16), dim3(64), 0, stream>>>(bp, bu, bl, out);
}

// Round 5
// 218.637 us; speedup vs baseline: 1.0876x; 1.0876x over previous
//
#include <hip/hip_runtime.h>
#include <hip/hip_bf16.h>

#define H  32
#define W  32
#define CI 32
#define CO 64
#define NB 8
#define NOUT 32

// d_out float offsets: [w_u | b_u | w_l | b_l]
#define WU_OFF 0
#define BU_OFF (NB * H * W * CI * NOUT)          // 8388608
#define WL_OFF (BU_OFF + NB * NOUT)              // 8388864
#define BL_OFF (WL_OFF + NB * H * W * CI * NOUT) // 16777472

// d_ws layout:
//   [0, 36864)       bf16 A-fragments (2304 uint4)
//   [36864, 38912)   fp32 bias partials bp[16][32]
#define KF_UINT4 2304
#define BP_OFF_BYTES 36864

typedef __bf16 bf16x8 __attribute__((ext_vector_type(8)));
typedef float  f32x4  __attribute__((ext_vector_type(4)));

__device__ __forceinline__ unsigned int pack_bf16(float lo, float hi) {
    unsigned int ulo = __float_as_uint(lo) + 0x8000u;
    unsigned int uhi = __float_as_uint(hi) + 0x8000u;
    return (uhi & 0xffff0000u) | (ulo >> 16);
}

// Swizzle conv kernel K[3][3][32][64] fp32 -> bf16 A-fragments (HW-verified R1-R4).
// Blocks 9,10 zero the fp32 bias-partial buffer.
__global__ void prep_kernel(const float* __restrict__ K,
                            unsigned int* __restrict__ kws,
                            float* __restrict__ bp) {
    int bx = blockIdx.x, t = threadIdx.x;
    if (bx < 9) {
        int g    = bx * 256 + t;
        int tap  = g >> 8;
        int r    = g & 255;
        int i    = r >> 3;
        int og   = r & 7;
        int c    = og >> 2;
        int quad = og & 3;
        int ih   = i >> 4;
        int lane = quad * 16 + (i & 15);
        int dst  = ((tap * 4 + c * 2 + ih) * 64 + lane) * 4;
        const float4* src = (const float4*)(K + (size_t)g * 8);
        float4 f0 = src[0];
        float4 f1 = src[1];
        kws[dst + 0] = pack_bf16(f0.x, f0.y);
        kws[dst + 1] = pack_bf16(f0.z, f0.w);
        kws[dst + 2] = pack_bf16(f1.x, f1.y);
        kws[dst + 3] = pack_bf16(f1.z, f1.w);
    } else {
        bp[(bx - 9) * 256 + t] = 0.f;
    }
}

// Fused transpose+conv v4: 256-thread blocks (4 waves), wave = one w-position,
// block = 4 w-positions. Halo 3x6 tiles -> stg 36.9 KB -> 4 blocks/CU =
// 16 waves/CU (2x R3's TLP) AND 4 independent barrier domains/CU (2x R3) --
// attacks the m233-style 2-phase stall via cross-block overlap.
// A-fragments read from global kws per tap inside `#pragma unroll 1` loops:
// prevents the R4 hoist-to-72-VGPR spill (WRITE_SIZE 68->168 MB scratch);
// kws is 36 KB, L1/L2-resident, all waves read identical addresses.
// Stage pattern / XOR swizzle (slot = og'*32 + ((n^(n>>2))^og'), b1 = rbase^20)
// / A/B/C-D fragment maps / store map byte-identical to R3 (verified, 0 conflicts).
__global__ __launch_bounds__(256, 4)
void fused_conv_kernel(const float* __restrict__ in0,
                       const float* __restrict__ in1,
                       const uint4* __restrict__ kws,
                       const float* __restrict__ bias,
                       float* __restrict__ bp,       // bp[16][32], pre-zeroed
                       float* __restrict__ out0,
                       float* __restrict__ out1) {
    __shared__ uint4 stg[18 * 128];    // 36864 B: [row*6+col][128 swizzled]
    __shared__ float bias_s[CO];
    __shared__ float bsum[4][32];      // per-wave bias partials

    int t = threadIdx.x;
    if (t < CO) bias_s[t] = bias[t];

    // XCD-aware swizzle: 4096 blocks, XCD = bx&7 gets 2 contiguous (side,b)
    // slabs, h-major walk inside -> concurrent window per XCD ~ half a slab
    // (~4 MB fp32) ~ L2-resident for halo re-reads.
    int bx    = blockIdx.x;
    int x     = bx & 7;
    int q     = bx >> 3;              // 0..511
    int combo = x * 2 + (q >> 8);     // (side,b) 0..15
    int inner = q & 255;
    int side  = combo >> 3;
    int b     = combo & 7;
    int h     = inner >> 3;           // 0..31
    int wq4   = inner & 7;            // w-quad 0..7

    const float* inp = (side ? in1 : in0) + (size_t)b * 1024 * 2048;
    const bf16x8* kfg = (const bf16x8*)kws;   // A-fragments straight from global

    // staging coords: unit (32 lanes) stages one tile; 8 units cover 18 tiles
    int unit = t >> 5;        // 0..7
    int ogp  = (t >> 3) & 3;  // og' within co-half
    int n4   = t & 7;
    // mfma coords: wave owns position w = wq4*4 + wave
    int wave = t >> 6;        // 0..3
    int lane = t & 63;
    int n16  = lane & 15;
    int quad = lane >> 4;
    int w    = wq4 * 4 + wave;

    f32x4 acc[2][2] = {};     // [ih][nh]
    float sb[4] = {0.f, 0.f, 0.f, 0.f};
    int rbase = quad * 32 + ((n16 ^ (n16 >> 2)) ^ quad);   // b1 slot = rbase^20

    __syncthreads();          // bias_s ready

    for (int c = 0; c < 2; c++) {
        // ---- stage c-half of 18 halo tiles (3 rows x 6 cols) ----
#pragma unroll 1
        for (int s = 0; s < 3; s++) {
            int tile = s * 8 + unit;          // 0..23
            if (tile < 18) {
                int row = tile < 6 ? 0 : (tile < 12 ? 1 : 2);
                int col = tile - row * 6;     // 0..5
                int hi  = h - 1 + row;
                int wi  = wq4 * 4 - 1 + col;
                if (hi >= 0 && hi < H && wi >= 0 && wi < W) {
                    const float* p = inp + (size_t)(hi * W + wi) * 2048
                                   + c * 1024 + ogp * 256 + n4 * 4;
                    float v[8][4];
#pragma unroll
                    for (int j = 0; j < 8; j++) {
                        float4 f = *(const float4*)(p + j * 32);  // 16 B/lane
                        v[j][0] = f.x; v[j][1] = f.y; v[j][2] = f.z; v[j][3] = f.w;
                    }
                    // bias einsum on owned positions only (row==1, col 1..4)
                    if (row == 1 && col >= 1 && col <= 4) {
#pragma unroll
                        for (int j = 0; j < 8; j++) {
                            float bj = bias_s[c * 32 + ogp * 8 + j];
#pragma unroll
                            for (int k = 0; k < 4; k++)
                                sb[k] = fmaf(v[j][k], bj, sb[k]);
                        }
                    }
                    uint4* dst = &stg[tile * 128 + ogp * 32];
#pragma unroll
                    for (int k = 0; k < 4; k++) {
                        uint4 u;
                        u.x = pack_bf16(v[0][k], v[1][k]);
                        u.y = pack_bf16(v[2][k], v[3][k]);
                        u.z = pack_bf16(v[4][k], v[5][k]);
                        u.w = pack_bf16(v[6][k], v[7][k]);
                        int n = n4 * 4 + k;
                        dst[(n ^ (n >> 2)) ^ ogp] = u;
                    }
                }
            }
        }
        __syncthreads();
        // ---- MFMA phase (verified fragment maps; A from global per tap) ----
        __builtin_amdgcn_s_setprio(1);
#pragma unroll 1
        for (int kh = 0; kh < 3; kh++) {
            int hi = h + 1 - kh;
            if (hi < 0 || hi >= H) continue;
            int row = 2 - kh;
#pragma unroll 1
            for (int kw = 0; kw < 3; kw++) {
                int wi = w + 1 - kw;
                if (wi < 0 || wi >= W) continue;
                int col = wave + 2 - kw;      // 0..5
                int tap = kh * 3 + kw;
                const uint4* Tp = &stg[(row * 6 + col) * 128];
                union { uint4 u; bf16x8 v; } b0, b1;
                b0.u = Tp[rbase];
                b1.u = Tp[rbase ^ 20];
                bf16x8 a0 = kfg[(tap * 4 + c * 2 + 0) * 64 + lane];
                bf16x8 a1 = kfg[(tap * 4 + c * 2 + 1) * 64 + lane];
                acc[0][0] = __builtin_amdgcn_mfma_f32_16x16x32_bf16(a0, b0.v, acc[0][0], 0, 0, 0);
                acc[0][1] = __builtin_amdgcn_mfma_f32_16x16x32_bf16(a0, b1.v, acc[0][1], 0, 0, 0);
                acc[1][0] = __builtin_amdgcn_mfma_f32_16x16x32_bf16(a1, b0.v, acc[1][0], 0, 0, 0);
                acc[1][1] = __builtin_amdgcn_mfma_f32_16x16x32_bf16(a1, b1.v, acc[1][1], 0, 0, 0);
            }
        }
        __builtin_amdgcn_s_setprio(0);
        if (c == 0) __syncthreads();          // protect stg overwrite
    }

    // bias: butterfly over lane bits 3,4,5, per-wave partials in LDS,
    // one 32-atomic set per block.
#pragma unroll
    for (int off = 8; off <= 32; off <<= 1)
#pragma unroll
        for (int k = 0; k < 4; k++)
            sb[k] += __shfl_xor(sb[k], off, 64);
    if (lane < 8) {
#pragma unroll
        for (int k = 0; k < 4; k++)
            bsum[wave][lane * 4 + k] = sb[k];
    }
    __syncthreads();
    if (t < 32) {
        float s = 0.f;
#pragma unroll
        for (int wv = 0; wv < 4; wv++) s += bsum[wv][t];
        atomicAdd(&bp[side * 256 + b * 32 + t], s);
    }

    // store (same per-lane map as verified R2/R3)
    float* outp = (side ? out1 : out0) + (size_t)b * (H * W * CI * NOUT);
    float* wout = outp + (size_t)((h * W + w) * CI) * NOUT;
#pragma unroll
    for (int ih = 0; ih < 2; ih++)
#pragma unroll
        for (int nh = 0; nh < 2; nh++)
#pragma unroll
            for (int r = 0; r < 4; r++) {
                int i = ih * 16 + quad * 4 + r;
                int n = nh * 16 + n16;
                wout[i * NOUT + n] = acc[ih][nh][r];
            }
}

// Bias finalize: b = b_in + bp
__global__ void bias_final32_kernel(const float* __restrict__ bp,
                                    const float* __restrict__ bu,
                                    const float* __restrict__ bl,
                                    float* __restrict__ out) {
    int sb = blockIdx.x;             // 0..15
    int t  = threadIdx.x;
    if (t >= NOUT) return;
    int side = sb >> 3, b = sb & 7;
    const float* bb = side ? bl : bu;
    out[(side ? BL_OFF : BU_OFF) + b * NOUT + t] =
        bb[b * NOUT + t] + bp[sb * 32 + t];
}

extern "C" void kernel_launch(void* const* d_in, const int* in_sizes, int n_in,
                              void* d_out, int out_size, void* d_ws, size_t ws_size,
                              hipStream_t stream) {
    const float* wu   = (const float*)d_in[0];
    const float* bu   = (const float*)d_in[1];
    const float* wl   = (const float*)d_in[2];
    const float* bl   = (const float*)d_in[3];
    const float* K    = (const float*)d_in[4];
    const float* bias = (const float*)d_in[5];
    float* out = (float*)d_out;
    unsigned int* kws = (unsigned int*)d_ws;
    float* bp = (float*)((char*)d_ws + BP_OFF_BYTES);

    prep_kernel<<<dim3(11), dim3(256), 0, stream>>>(K, kws, bp);
    fused_conv_kernel<<<dim3(4096), dim3(256), 0, stream>>>(
        wu, wl, (const uint4*)d_ws, bias, bp, out + WU_OFF, out + WL_OFF);
    bias_final32_kernel<<<dim3(16), dim3(64), 0, stream>>>(bp, bu, bl, out);
}

// Round 6
// 210.997 us; speedup vs baseline: 1.1270x; 1.0362x over previous
//
#include <hip/hip_runtime.h>
#include <hip/hip_bf16.h>

#define H  32
#define W  32
#define CI 32
#define CO 64
#define NB 8
#define NOUT 32

// d_out float offsets: [w_u | b_u | w_l | b_l]
#define WU_OFF 0
#define BU_OFF (NB * H * W * CI * NOUT)          // 8388608
#define WL_OFF (BU_OFF + NB * NOUT)              // 8388864
#define BL_OFF (WL_OFF + NB * H * W * CI * NOUT) // 16777472

// d_ws layout:
//   [0, 36864)       bf16 A-fragments (2304 uint4)
//   [36864, 38912)   fp32 bias partials bp[16][32]
#define KF_UINT4 2304
#define BP_OFF_BYTES 36864

typedef __bf16 bf16x8 __attribute__((ext_vector_type(8)));
typedef float  f32x4  __attribute__((ext_vector_type(4)));

__device__ __forceinline__ unsigned int pack_bf16(float lo, float hi) {
    unsigned int ulo = __float_as_uint(lo) + 0x8000u;
    unsigned int uhi = __float_as_uint(hi) + 0x8000u;
    return (uhi & 0xffff0000u) | (ulo >> 16);
}

// Swizzle conv kernel K[3][3][32][64] fp32 -> bf16 A-fragments (HW-verified R1-R4).
// Blocks 9,10 zero the fp32 bias-partial buffer.
__global__ void prep_kernel(const float* __restrict__ K,
                            unsigned int* __restrict__ kws,
                            float* __restrict__ bp) {
    int bx = blockIdx.x, t = threadIdx.x;
    if (bx < 9) {
        int g    = bx * 256 + t;
        int tap  = g >> 8;
        int r    = g & 255;
        int i    = r >> 3;
        int og   = r & 7;
        int c    = og >> 2;
        int quad = og & 3;
        int ih   = i >> 4;
        int lane = quad * 16 + (i & 15);
        int dst  = ((tap * 4 + c * 2 + ih) * 64 + lane) * 4;
        const float4* src = (const float4*)(K + (size_t)g * 8);
        float4 f0 = src[0];
        float4 f1 = src[1];
        kws[dst + 0] = pack_bf16(f0.x, f0.y);
        kws[dst + 1] = pack_bf16(f0.z, f0.w);
        kws[dst + 2] = pack_bf16(f1.x, f1.y);
        kws[dst + 3] = pack_bf16(f1.z, f1.w);
    } else {
        bp[(bx - 9) * 256 + t] = 0.f;
    }
}

// Fused transpose+conv v5: 512-thread blocks (8 waves), block = 2x4 (h x w)
// output patch, wave = one position. Halo 4x6 c-half tiles = 49.2 KB LDS
// -> 3 blocks/CU = 24 waves/CU (R5 had 16) and halo-staging redundancy
// drops 4.5 -> 3.0 tiles/position. VGPR must stay <=85 for 6 waves/SIMD:
// __launch_bounds__(512,6); A-fragments stay global-per-tap (L1/L2-hot) to
// avoid the R4 hoist-spill. kw-loop fully unrolled for ILP (3 iterations'
// ds_reads/A-loads overlap); kh stays unroll 1 to bound live registers.
// Stage pattern / XOR swizzle (slot = og'*32 + ((n^(n>>2))^og'), b1 = rbase^20)
// / A/B/C-D fragment maps / store map byte-identical to R3-R5 (verified).
__global__ __launch_bounds__(512, 6)
void fused_conv_kernel(const float* __restrict__ in0,
                       const float* __restrict__ in1,
                       const uint4* __restrict__ kws,
                       const float* __restrict__ bias,
                       float* __restrict__ bp,       // bp[16][32], pre-zeroed
                       float* __restrict__ out0,
                       float* __restrict__ out1) {
    __shared__ uint4 stg[24 * 128];    // 49152 B: [row*6+col][128 swizzled]
    __shared__ float bias_s[CO];
    __shared__ float bsum[8][32];      // per-wave bias partials

    int t = threadIdx.x;
    if (t < CO) bias_s[t] = bias[t];

    // XCD-aware swizzle: 2048 blocks, XCD = bx&7 gets 2 contiguous (side,b)
    // slabs, h-major walk inside -> 4-row fp32 window per XCD ~ L2-resident.
    int bx    = blockIdx.x;
    int x     = bx & 7;
    int q     = bx >> 3;              // 0..255
    int combo = x * 2 + (q >> 7);     // (side,b) 0..15
    int inner = q & 127;
    int side  = combo >> 3;
    int b     = combo & 7;
    int h0    = (inner >> 3) * 2;     // 0,2,..,30
    int wq4   = inner & 7;            // w-quad 0..7

    const float* inp = (side ? in1 : in0) + (size_t)b * 1024 * 2048;
    const bf16x8* kfg = (const bf16x8*)kws;   // A-fragments straight from global

    // staging coords: unit (32 lanes) stages one tile; 16 units, 24 tiles, 2 steps
    int unit = t >> 5;        // 0..15
    int ogp  = (t >> 3) & 3;  // og' within co-half
    int n4   = t & 7;
    // mfma coords: wave owns position (h, w)
    int wave = t >> 6;        // 0..7
    int lane = t & 63;
    int n16  = lane & 15;
    int quad = lane >> 4;
    int wl   = wave & 3;
    int wh2  = wave >> 2;
    int h    = h0 + wh2;
    int w    = wq4 * 4 + wl;

    f32x4 acc[2][2] = {};     // [ih][nh]
    float sb[4] = {0.f, 0.f, 0.f, 0.f};
    int rbase = quad * 32 + ((n16 ^ (n16 >> 2)) ^ quad);   // b1 slot = rbase^20

    __syncthreads();          // bias_s ready

    for (int c = 0; c < 2; c++) {
        // ---- stage c-half of 24 halo tiles (4 rows x 6 cols) ----
#pragma unroll 1
        for (int s = 0; s < 2; s++) {
            int tile = s * 16 + unit;         // 0..31
            if (tile < 24) {
                int row = tile >= 18 ? 3 : (tile >= 12 ? 2 : (tile >= 6 ? 1 : 0));
                int col = tile - row * 6;     // 0..5
                int hi  = h0 - 1 + row;
                int wi  = wq4 * 4 - 1 + col;
                if (hi >= 0 && hi < H && wi >= 0 && wi < W) {
                    const float* p = inp + (size_t)(hi * W + wi) * 2048
                                   + c * 1024 + ogp * 256 + n4 * 4;
                    float v[8][4];
#pragma unroll
                    for (int j = 0; j < 8; j++) {
                        float4 f = *(const float4*)(p + j * 32);  // 16 B/lane
                        v[j][0] = f.x; v[j][1] = f.y; v[j][2] = f.z; v[j][3] = f.w;
                    }
                    // bias einsum on owned positions only (rows 1,2 = own rows,
                    // cols 1..4 = own cols -> exactly-once global coverage)
                    if ((row == 1 || row == 2) && col >= 1 && col <= 4) {
#pragma unroll
                        for (int j = 0; j < 8; j++) {
                            float bj = bias_s[c * 32 + ogp * 8 + j];
#pragma unroll
                            for (int k = 0; k < 4; k++)
                                sb[k] = fmaf(v[j][k], bj, sb[k]);
                        }
                    }
                    uint4* dst = &stg[tile * 128 + ogp * 32];
#pragma unroll
                    for (int k = 0; k < 4; k++) {
                        uint4 u;
                        u.x = pack_bf16(v[0][k], v[1][k]);
                        u.y = pack_bf16(v[2][k], v[3][k]);
                        u.z = pack_bf16(v[4][k], v[5][k]);
                        u.w = pack_bf16(v[6][k], v[7][k]);
                        int n = n4 * 4 + k;
                        dst[(n ^ (n >> 2)) ^ ogp] = u;
                    }
                }
            }
        }
        __syncthreads();
        // ---- MFMA phase (verified fragment maps; A from global per tap) ----
        __builtin_amdgcn_s_setprio(1);
#pragma unroll 1
        for (int kh = 0; kh < 3; kh++) {
            int hi = h + 1 - kh;
            if (hi < 0 || hi >= H) continue;
            int row = wh2 + 2 - kh;           // row in stg (0..3)
#pragma unroll
            for (int kw = 0; kw < 3; kw++) {
                int wi = w + 1 - kw;
                if (wi < 0 || wi >= W) continue;
                int col = wl + 2 - kw;        // 0..5
                int tap = kh * 3 + kw;
                const uint4* Tp = &stg[(row * 6 + col) * 128];
                union { uint4 u; bf16x8 v; } b0, b1;
                b0.u = Tp[rbase];
                b1.u = Tp[rbase ^ 20];
                bf16x8 a0 = kfg[(tap * 4 + c * 2 + 0) * 64 + lane];
                bf16x8 a1 = kfg[(tap * 4 + c * 2 + 1) * 64 + lane];
                acc[0][0] = __builtin_amdgcn_mfma_f32_16x16x32_bf16(a0, b0.v, acc[0][0], 0, 0, 0);
                acc[0][1] = __builtin_amdgcn_mfma_f32_16x16x32_bf16(a0, b1.v, acc[0][1], 0, 0, 0);
                acc[1][0] = __builtin_amdgcn_mfma_f32_16x16x32_bf16(a1, b0.v, acc[1][0], 0, 0, 0);
                acc[1][1] = __builtin_amdgcn_mfma_f32_16x16x32_bf16(a1, b1.v, acc[1][1], 0, 0, 0);
            }
        }
        __builtin_amdgcn_s_setprio(0);
        if (c == 0) __syncthreads();          // protect stg overwrite
    }

    // bias: butterfly over lane bits 3,4,5, per-wave partials in LDS,
    // one 32-atomic set per block.
#pragma unroll
    for (int off = 8; off <= 32; off <<= 1)
#pragma unroll
        for (int k = 0; k < 4; k++)
            sb[k] += __shfl_xor(sb[k], off, 64);
    if (lane < 8) {
#pragma unroll
        for (int k = 0; k < 4; k++)
            bsum[wave][lane * 4 + k] = sb[k];
    }
    __syncthreads();
    if (t < 32) {
        float s = 0.f;
#pragma unroll
        for (int wv = 0; wv < 8; wv++) s += bsum[wv][t];
        atomicAdd(&bp[side * 256 + b * 32 + t], s);
    }

    // store (same per-lane map as verified R2-R5)
    float* outp = (side ? out1 : out0) + (size_t)b * (H * W * CI * NOUT);
    float* wout = outp + (size_t)((h * W + w) * CI) * NOUT;
#pragma unroll
    for (int ih = 0; ih < 2; ih++)
#pragma unroll
        for (int nh = 0; nh < 2; nh++)
#pragma unroll
            for (int r = 0; r < 4; r++) {
                int i = ih * 16 + quad * 4 + r;
                int n = nh * 16 + n16;
                wout[i * NOUT + n] = acc[ih][nh][r];
            }
}

// Bias finalize: b = b_in + bp
__global__ void bias_final32_kernel(const float* __restrict__ bp,
                                    const float* __restrict__ bu,
                                    const float* __restrict__ bl,
                                    float* __restrict__ out) {
    int sb = blockIdx.x;             // 0..15
    int t  = threadIdx.x;
    if (t >= NOUT) return;
    int side = sb >> 3, b = sb & 7;
    const float* bb = side ? bl : bu;
    out[(side ? BL_OFF : BU_OFF) + b * NOUT + t] =
        bb[b * NOUT + t] + bp[sb * 32 + t];
}

extern "C" void kernel_launch(void* const* d_in, const int* in_sizes, int n_in,
                              void* d_out, int out_size, void* d_ws, size_t ws_size,
                              hipStream_t stream) {
    const float* wu   = (const float*)d_in[0];
    const float* bu   = (const float*)d_in[1];
    const float* wl   = (const float*)d_in[2];
    const float* bl   = (const float*)d_in[3];
    const float* K    = (const float*)d_in[4];
    const float* bias = (const float*)d_in[5];
    float* out = (float*)d_out;
    unsigned int* kws = (unsigned int*)d_ws;
    float* bp = (float*)((char*)d_ws + BP_OFF_BYTES);

    prep_kernel<<<dim3(11), dim3(256), 0, stream>>>(K, kws, bp);
    fused_conv_kernel<<<dim3(2048), dim3(512), 0, stream>>>(
        wu, wl, (const uint4*)d_ws, bias, bp, out + WU_OFF, out + WL_OFF);
    bias_final32_kernel<<<dim3(16), dim3(64), 0, stream>>>(bp, bu, bl, out);
}

// Round 7
// 204.902 us; speedup vs baseline: 1.1605x; 1.0297x over previous
//
#include <hip/hip_runtime.h>
#include <hip/hip_bf16.h>

#define H  32
#define W  32
#define CI 32
#define CO 64
#define NB 8
#define NOUT 32

// d_out float offsets: [w_u | b_u | w_l | b_l]
#define WU_OFF 0
#define BU_OFF (NB * H * W * CI * NOUT)          // 8388608
#define WL_OFF (BU_OFF + NB * NOUT)              // 8388864
#define BL_OFF (WL_OFF + NB * H * W * CI * NOUT) // 16777472

// d_ws layout:
//   [0, 36864)       bf16 A-fragments (2304 uint4)
//   [36864, 38912)   fp32 bias partials bp[16][32]
#define KF_UINT4 2304
#define BP_OFF_BYTES 36864

typedef __bf16 bf16x8 __attribute__((ext_vector_type(8)));
typedef float  f32x4  __attribute__((ext_vector_type(4)));

__device__ __forceinline__ unsigned int pack_bf16(float lo, float hi) {
    unsigned int ulo = __float_as_uint(lo) + 0x8000u;
    unsigned int uhi = __float_as_uint(hi) + 0x8000u;
    return (uhi & 0xffff0000u) | (ulo >> 16);
}

// Swizzle conv kernel K[3][3][32][64] fp32 -> bf16 A-fragments (HW-verified R1-R4).
// Blocks 9,10 zero the fp32 bias-partial buffer.
__global__ void prep_kernel(const float* __restrict__ K,
                            unsigned int* __restrict__ kws,
                            float* __restrict__ bp) {
    int bx = blockIdx.x, t = threadIdx.x;
    if (bx < 9) {
        int g    = bx * 256 + t;
        int tap  = g >> 8;
        int r    = g & 255;
        int i    = r >> 3;
        int og   = r & 7;
        int c    = og >> 2;
        int quad = og & 3;
        int ih   = i >> 4;
        int lane = quad * 16 + (i & 15);
        int dst  = ((tap * 4 + c * 2 + ih) * 64 + lane) * 4;
        const float4* src = (const float4*)(K + (size_t)g * 8);
        float4 f0 = src[0];
        float4 f1 = src[1];
        kws[dst + 0] = pack_bf16(f0.x, f0.y);
        kws[dst + 1] = pack_bf16(f0.z, f0.w);
        kws[dst + 2] = pack_bf16(f1.x, f1.y);
        kws[dst + 3] = pack_bf16(f1.z, f1.w);
    } else {
        bp[(bx - 9) * 256 + t] = 0.f;
    }
}

__device__ __forceinline__ void load_tile(const float* p, int c, float v[8][4]) {
#pragma unroll
    for (int j = 0; j < 8; j++) {
        float4 f = *(const float4*)(p + c * 1024 + j * 32);   // 16 B/lane coalesced
        v[j][0] = f.x; v[j][1] = f.y; v[j][2] = f.z; v[j][3] = f.w;
    }
}

__device__ __forceinline__ void pack_write(const float v[8][4], int tile,
                                           int ogp, int n4, uint4* stg) {
    uint4* dst = &stg[tile * 128 + ogp * 32];
#pragma unroll
    for (int k = 0; k < 4; k++) {
        uint4 u;
        u.x = pack_bf16(v[0][k], v[1][k]);
        u.y = pack_bf16(v[2][k], v[3][k]);
        u.z = pack_bf16(v[4][k], v[5][k]);
        u.w = pack_bf16(v[6][k], v[7][k]);
        int n = n4 * 4 + k;
        dst[(n ^ (n >> 2)) ^ ogp] = u;     // verified conflict-free swizzle
    }
}

__device__ __forceinline__ void bias_acc(const float v[8][4], const float* bias_s,
                                         int c, int ogp, float sb[4]) {
#pragma unroll
    for (int j = 0; j < 8; j++) {
        float bj = bias_s[c * 32 + ogp * 8 + j];
#pragma unroll
        for (int k = 0; k < 4; k++)
            sb[k] = fmaf(v[j][k], bj, sb[k]);
    }
}

__device__ __forceinline__ void mfma_phase(int c, int h, int w, int wh2, int wl,
                                           int rbase, int lane,
                                           const uint4* stg, const bf16x8* kfg,
                                           f32x4 acc[2][2]) {
    __builtin_amdgcn_s_setprio(1);
#pragma unroll 1
    for (int kh = 0; kh < 3; kh++) {
        int hi = h + 1 - kh;
        if (hi < 0 || hi >= H) continue;
        int row = wh2 + 2 - kh;               // row in stg (0..3)
#pragma unroll
        for (int kw = 0; kw < 3; kw++) {
            int wi = w + 1 - kw;
            if (wi < 0 || wi >= W) continue;
            int col = wl + 2 - kw;            // 0..5
            int tap = kh * 3 + kw;
            const uint4* Tp = &stg[(row * 6 + col) * 128];
            union { uint4 u; bf16x8 v; } b0, b1;
            b0.u = Tp[rbase];
            b1.u = Tp[rbase ^ 20];
            bf16x8 a0 = kfg[(tap * 4 + c * 2 + 0) * 64 + lane];
            bf16x8 a1 = kfg[(tap * 4 + c * 2 + 1) * 64 + lane];
            acc[0][0] = __builtin_amdgcn_mfma_f32_16x16x32_bf16(a0, b0.v, acc[0][0], 0, 0, 0);
            acc[0][1] = __builtin_amdgcn_mfma_f32_16x16x32_bf16(a0, b1.v, acc[0][1], 0, 0, 0);
            acc[1][0] = __builtin_amdgcn_mfma_f32_16x16x32_bf16(a1, b0.v, acc[1][0], 0, 0, 0);
            acc[1][1] = __builtin_amdgcn_mfma_f32_16x16x32_bf16(a1, b1.v, acc[1][1], 0, 0, 0);
        }
    }
    __builtin_amdgcn_s_setprio(0);
}

// Fused transpose+conv v6 (T14 pipeline): 512-thread blocks, block = 2x4
// (h x w) output patch, wave = one position, halo 4x6 c-half tiles (49.2 KB).
// Pipeline: issue c0 loads -> pack/write c0 -> ISSUE c1 LOADS (into freed
// regs) -> barrier -> MFMA c0 (c1 loads in flight underneath, ~600cy latency
// hidden by ~1000+cy of MFMA/ds_read/A-loads) -> barrier -> pack/write c1
// (no load-wait left) -> barrier -> MFMA c1. Removes one of two exposed
// HBM-latency stalls per block (m214v27 analog).
// __launch_bounds__(512,4): 128-VGPR cap holds the ~48-64 VGPR in-flight tile
// set without the R6 spill (R6: cap 84 -> WRITE_SIZE 66->94.5 MB scratch).
// Stage pattern / XOR swizzle (slot = og'*32 + ((n^(n>>2))^og'), b1 = rbase^20)
// / A/B/C-D fragment maps / store map byte-identical to R3-R6 (verified).
__global__ __launch_bounds__(512, 4)
void fused_conv_kernel(const float* __restrict__ in0,
                       const float* __restrict__ in1,
                       const uint4* __restrict__ kws,
                       const float* __restrict__ bias,
                       float* __restrict__ bp,       // bp[16][32], pre-zeroed
                       float* __restrict__ out0,
                       float* __restrict__ out1) {
    __shared__ uint4 stg[24 * 128];    // 49152 B: [row*6+col][128 swizzled]
    __shared__ float bias_s[CO];
    __shared__ float bsum[8][32];      // per-wave bias partials

    int t = threadIdx.x;
    if (t < CO) bias_s[t] = bias[t];

    // XCD-aware swizzle: 2048 blocks, XCD = bx&7 gets 2 contiguous (side,b)
    // slabs, h-major walk inside -> 4-row fp32 window per XCD ~ L2-resident.
    int bx    = blockIdx.x;
    int x     = bx & 7;
    int q     = bx >> 3;              // 0..255
    int combo = x * 2 + (q >> 7);     // (side,b) 0..15
    int inner = q & 127;
    int side  = combo >> 3;
    int b     = combo & 7;
    int h0    = (inner >> 3) * 2;     // 0,2,..,30
    int wq4   = inner & 7;            // w-quad 0..7

    const float* inp = (side ? in1 : in0) + (size_t)b * 1024 * 2048;
    const bf16x8* kfg = (const bf16x8*)kws;   // A-fragments straight from global

    // staging coords: unit (32 lanes) owns tile A = unit and tile B = unit+16
    int unit = t >> 5;        // 0..15
    int ogp  = (t >> 3) & 3;  // og' within co-half
    int n4   = t & 7;
    // mfma coords: wave owns position (h, w)
    int wave = t >> 6;        // 0..7
    int lane = t & 63;
    int n16  = lane & 15;
    int quad = lane >> 4;
    int wl   = wave & 3;
    int wh2  = wave >> 2;
    int h    = h0 + wh2;
    int w    = wq4 * 4 + wl;

    // per-tile precompute (tile ids: A = unit in 0..15, B = unit+16 in 16..31)
    int tA   = unit;
    int rowA = tA >= 12 ? 2 : (tA >= 6 ? 1 : 0);
    int colA = tA - rowA * 6;
    int tB   = unit + 16;
    int rowB = tB >= 18 ? 3 : 2;
    int colB = tB - rowB * 6;
    int hiA = h0 - 1 + rowA, wiA = wq4 * 4 - 1 + colA;
    int hiB = h0 - 1 + rowB, wiB = wq4 * 4 - 1 + colB;
    bool okA = (hiA >= 0 && hiA < H && wiA >= 0 && wiA < W);
    bool okB = (tB < 24) && (hiB >= 0 && hiB < H && wiB >= 0 && wiB < W);
    const float* pA = inp + (size_t)((hiA * W + wiA)) * 2048 + ogp * 256 + n4 * 4;
    const float* pB = inp + (size_t)((hiB * W + wiB)) * 2048 + ogp * 256 + n4 * 4;
    // bias ownership: rows 1,2 (own output rows), cols 1..4 -> exactly-once
    bool ownA = (rowA == 1 || rowA == 2) && colA >= 1 && colA <= 4;
    bool ownB = (rowB == 2) && colB >= 1 && colB <= 4;

    f32x4 acc[2][2] = {};     // [ih][nh]
    float sb[4] = {0.f, 0.f, 0.f, 0.f};
    int rbase = quad * 32 + ((n16 ^ (n16 >> 2)) ^ quad);   // b1 slot = rbase^20

    float vA[8][4], vB[8][4];

    // ---- issue c0 loads ----
    if (okA) load_tile(pA, 0, vA);
    if (okB) load_tile(pB, 0, vB);
    __syncthreads();          // bias_s ready
    // ---- pack/write c0 (+bias), then issue c1 loads into freed regs ----
    if (okA) { if (ownA) bias_acc(vA, bias_s, 0, ogp, sb); pack_write(vA, tA, ogp, n4, stg); }
    if (okB) { if (ownB) bias_acc(vB, bias_s, 0, ogp, sb); pack_write(vB, tB, ogp, n4, stg); }
    if (okA) load_tile(pA, 1, vA);
    if (okB) load_tile(pB, 1, vB);
    __syncthreads();          // stg c0 complete
    // ---- MFMA c0 (c1 loads in flight underneath) ----
    mfma_phase(0, h, w, wh2, wl, rbase, lane, stg, kfg, acc);
    __syncthreads();          // all reads of stg c0 done
    // ---- pack/write c1 (loads long since landed) ----
    if (okA) { if (ownA) bias_acc(vA, bias_s, 1, ogp, sb); pack_write(vA, tA, ogp, n4, stg); }
    if (okB) { if (ownB) bias_acc(vB, bias_s, 1, ogp, sb); pack_write(vB, tB, ogp, n4, stg); }
    __syncthreads();          // stg c1 complete
    // ---- MFMA c1 ----
    mfma_phase(1, h, w, wh2, wl, rbase, lane, stg, kfg, acc);

    // bias: butterfly over lane bits 3,4,5, per-wave partials in LDS,
    // one 32-atomic set per block.
#pragma unroll
    for (int off = 8; off <= 32; off <<= 1)
#pragma unroll
        for (int k = 0; k < 4; k++)
            sb[k] += __shfl_xor(sb[k], off, 64);
    if (lane < 8) {
#pragma unroll
        for (int k = 0; k < 4; k++)
            bsum[wave][lane * 4 + k] = sb[k];
    }
    __syncthreads();
    if (t < 32) {
        float s = 0.f;
#pragma unroll
        for (int wv = 0; wv < 8; wv++) s += bsum[wv][t];
        atomicAdd(&bp[side * 256 + b * 32 + t], s);
    }

    // store (same per-lane map as verified R2-R6)
    float* outp = (side ? out1 : out0) + (size_t)b * (H * W * CI * NOUT);
    float* wout = outp + (size_t)((h * W + w) * CI) * NOUT;
#pragma unroll
    for (int ih = 0; ih < 2; ih++)
#pragma unroll
        for (int nh = 0; nh < 2; nh++)
#pragma unroll
            for (int r = 0; r < 4; r++) {
                int i = ih * 16 + quad * 4 + r;
                int n = nh * 16 + n16;
                wout[i * NOUT + n] = acc[ih][nh][r];
            }
}

// Bias finalize: b = b_in + bp
__global__ void bias_final32_kernel(const float* __restrict__ bp,
                                    const float* __restrict__ bu,
                                    const float* __restrict__ bl,
                                    float* __restrict__ out) {
    int sb = blockIdx.x;             // 0..15
    int t  = threadIdx.x;
    if (t >= NOUT) return;
    int side = sb >> 3, b = sb & 7;
    const float* bb = side ? bl : bu;
    out[(side ? BL_OFF : BU_OFF) + b * NOUT + t] =
        bb[b * NOUT + t] + bp[sb * 32 + t];
}

extern "C" void kernel_launch(void* const* d_in, const int* in_sizes, int n_in,
                              void* d_out, int out_size, void* d_ws, size_t ws_size,
                              hipStream_t stream) {
    const float* wu   = (const float*)d_in[0];
    const float* bu   = (const float*)d_in[1];
    const float* wl   = (const float*)d_in[2];
    const float* bl   = (const float*)d_in[3];
    const float* K    = (const float*)d_in[4];
    const float* bias = (const float*)d_in[5];
    float* out = (float*)d_out;
    unsigned int* kws = (unsigned int*)d_ws;
    float* bp = (float*)((char*)d_ws + BP_OFF_BYTES);

    prep_kernel<<<dim3(11), dim3(256), 0, stream>>>(K, kws, bp);
    fused_conv_kernel<<<dim3(2048), dim3(512), 0, stream>>>(
        wu, wl, (const uint4*)d_ws, bias, bp, out + WU_OFF, out + WL_OFF);
    bias_final32_kernel<<<dim3(16), dim3(64), 0, stream>>>(bp, bu, bl, out);
}